// Round 9
// baseline (160.182 us; speedup 1.0000x reference)
//
#include <hip/hip_runtime.h>

// B=4, T=2048, C=1024, H=64. fp32 in/out, bf16 MFMA internally.
// ws layout (u16 elements):
//   [0,        524288)  q  bf16  [b*2048+t][64]
//   [524288,  1048576)  k  bf16  [b*2048+t][64]
//   [1048576, 1572864)  vT bf16  [b][h][t]   (b*131072 + h*2048 + t)
//   [1572864, 1769472)  wT bf16  [sel][h][c] (sel*65536 + h*1024 + c)
//   byte 4 MB: 48 u32 ready-tokens (poison-safe MAGIC handshake)
//
// Round-9 = round-6/7/8 resubmission (all died on GPU acquisition timeout;
// kernel never ran). 2 launches instead of 3: wtrans merged into proj as
// blocks 0..47 with a 48-token device-scope release/acquire handshake; every
// block issues its x prefetch BEFORE polling so the transpose hides under
// the x HBM traffic. Round-5 attribution: setprio neutral -> removed;
// proj-16 split was round-4's regressor -> proj stays at proven 32-row body.
// Full grid.sync fusion measured-dead (round-2: ~125 us/sync spin).

typedef __attribute__((ext_vector_type(8))) short short8;
typedef __attribute__((ext_vector_type(4))) float f32x4;

#define NTOT 524288   // 8192*64
#define WT_OFF (3 * NTOT)
#define TOKEN_MAGIC 0x4D5A9E21u     // 4 distinct bytes: no byte/dword poison fill can alias it
#define TOKEN_U16_OFF 2097152       // byte offset 4 MB into ws (past wT end at 1966080)

__device__ __forceinline__ unsigned short f2bf(float f) {
    unsigned int u = __builtin_bit_cast(unsigned int, f);
    return (unsigned short)((u + 0x7fffu + ((u >> 16) & 1u)) >> 16);
}

__device__ __forceinline__ short8 pack8(float4 a, float4 b) {
    short8 r;
    r[0] = (short)f2bf(a.x); r[1] = (short)f2bf(a.y);
    r[2] = (short)f2bf(a.z); r[3] = (short)f2bf(a.w);
    r[4] = (short)f2bf(b.x); r[5] = (short)f2bf(b.y);
    r[6] = (short)f2bf(b.z); r[7] = (short)f2bf(b.w);
    return r;
}

// ---------------------------------------------------------------------------
// Kernel 1: fused W-transpose + projections. 256 blocks x 512 threads.
// Blocks 0..47 first transpose one 64-column tile of one W matrix
// (fp32 [1024][64] -> wT bf16 [64][1024]) and publish a release token.
// All 256 blocks: issue x prefetch, poll the 48 tokens (acquire), then run
// the proven 32-row proj body (4 iters of 24 MFMA + cross-wave LDS reduce).
// Deadlock-safe: 67.6 KB LDS + ~190 VGPR -> exactly 1 block/CU, grid 256 =
// capacity 256, all blocks co-resident; producers are the first dispatched.
// ---------------------------------------------------------------------------
__global__ __launch_bounds__(512) void projw_kernel(
    const float* __restrict__ x, const float* __restrict__ Wq,
    const float* __restrict__ Wk, const float* __restrict__ Wv,
    unsigned short* __restrict__ ws)
{
    const int blk  = blockIdx.x;
    const int m0   = blk * 32;
    const int tid  = threadIdx.x;
    const int wave = tid >> 6, lane = tid & 63;   // wave 0..7
    const int quad = lane >> 4, l16 = lane & 15;

    unsigned short* wt = ws + WT_OFF;
    unsigned int* tokens = (unsigned int*)(ws + TOKEN_U16_OFF);

    // shared scratch:
    //   wtrans phase (blocks 0..47): u16 tile[64][72] = 9216 B (aliased)
    //   q/k phases: [8][32][66] floats; v phase: [8][64][33] floats
    __shared__ float lds[16896];   // 67.6 KB

    // ---- phase A: W transpose (blocks 0..47 only; block-uniform branch) ----
    if (blk < 48) {
        const int sel = blk >> 4;            // 0..2
        const int c0  = (blk & 15) * 64;     // 0..960
        const float* W = (sel == 0) ? Wq : ((sel == 1) ? Wk : Wv);
        unsigned short (*tile)[72] = (unsigned short (*)[72])lds;
        if (tid < 256) {
            const int c  = tid >> 2;
            const int hg = (tid & 3) * 16;
            const float* src = W + (size_t)(c0 + c) * 64 + hg;
            #pragma unroll
            for (int i = 0; i < 16; i++) tile[c][hg + i] = f2bf(src[i]);
        }
        __syncthreads();
        if (tid < 256) {
            const int h   = tid >> 2;
            const int cg0 = (tid & 3) * 16;
            unsigned short* dst = wt + ((size_t)sel * 64 + h) * 1024 + c0 + cg0;
            #pragma unroll
            for (int i = 0; i < 16; i++) dst[i] = tile[cg0 + i][h];
        }
        __syncthreads();   // drains vmcnt: all wT stores of this block issued
        if (tid == 0) {
            __threadfence();   // agent-scope release: write back producer L2
            __hip_atomic_store(&tokens[blk], TOKEN_MAGIC,
                               __ATOMIC_RELEASE, __HIP_MEMORY_SCOPE_AGENT);
        }
    }

    const unsigned short* wq = wt;
    const unsigned short* wk = wt + 65536;
    const unsigned short* wv = wt + 131072;

    // ---- issue x prefetch BEFORE waiting: transpose hides under HBM ----
    const int kbase = wave * 128;
    const float* xrow0 = x + (size_t)(m0 + l16) * 1024 + kbase + quad * 8;
    const float* xrow1 = xrow0 + (size_t)16 * 1024;
    float4 xa0 = *(const float4*)(xrow0);
    float4 xb0 = *(const float4*)(xrow0 + 4);
    float4 xa1 = *(const float4*)(xrow1);
    float4 xb1 = *(const float4*)(xrow1 + 4);

    // ---- wait for all 48 wT tiles (acquire) ----
    if (tid < 48) {
        while (__hip_atomic_load(&tokens[tid], __ATOMIC_ACQUIRE,
                                 __HIP_MEMORY_SCOPE_AGENT) != TOKEN_MAGIC)
            __builtin_amdgcn_s_sleep(1);
    }
    __syncthreads();
    __threadfence();   // acquire side for all threads: invalidate stale lines

    // ---- proven 32-row proj body ----
    f32x4 aq[2][4] = {}, ak[2][4] = {}, av[4][2] = {};

    for (int kk = 0; kk < 128; kk += 32) {
        const int nk = (kk + 32) & 127;     // wraps on last iter (unused)
        float4 na0 = *(const float4*)(xrow0 + nk);
        float4 nb0 = *(const float4*)(xrow0 + nk + 4);
        float4 na1 = *(const float4*)(xrow1 + nk);
        float4 nb1 = *(const float4*)(xrow1 + nk + 4);
        short8 af0 = pack8(xa0, xb0);
        short8 af1 = pack8(xa1, xb1);
        const int wo = kbase + kk + quad * 8;
        #pragma unroll
        for (int nt = 0; nt < 4; nt++) {
            const size_t ro = (size_t)(nt * 16 + l16) * 1024 + wo;
            short8 bq = *(const short8*)(wq + ro);
            short8 bk = *(const short8*)(wk + ro);
            short8 bv = *(const short8*)(wv + ro);
            aq[0][nt] = __builtin_amdgcn_mfma_f32_16x16x32_bf16(af0, bq, aq[0][nt], 0, 0, 0);
            aq[1][nt] = __builtin_amdgcn_mfma_f32_16x16x32_bf16(af1, bq, aq[1][nt], 0, 0, 0);
            ak[0][nt] = __builtin_amdgcn_mfma_f32_16x16x32_bf16(af0, bk, ak[0][nt], 0, 0, 0);
            ak[1][nt] = __builtin_amdgcn_mfma_f32_16x16x32_bf16(af1, bk, ak[1][nt], 0, 0, 0);
            av[nt][0] = __builtin_amdgcn_mfma_f32_16x16x32_bf16(bv, af0, av[nt][0], 0, 0, 0);
            av[nt][1] = __builtin_amdgcn_mfma_f32_16x16x32_bf16(bv, af1, av[nt][1], 0, 0, 0);
        }
        xa0 = na0; xb0 = nb0; xa1 = na1; xb1 = nb1;
    }

    const int b   = m0 >> 11;
    const int tb0 = m0 & 2047;
    const int rrow = tid >> 4, rh0 = (tid & 15) * 4;   // q/k reduce mapping

    __syncthreads();   // uniform re-convergence point before LDS reuse

    // ---- phase Q: stash, reduce 8-way, store ----
    #pragma unroll
    for (int tf = 0; tf < 2; tf++)
        #pragma unroll
        for (int nt = 0; nt < 4; nt++)
            #pragma unroll
            for (int r = 0; r < 4; r++)
                lds[(wave * 32 + tf * 16 + quad * 4 + r) * 66 + nt * 16 + l16]
                    = aq[tf][nt][r];
    __syncthreads();
    {
        float s[4] = {0.f, 0.f, 0.f, 0.f};
        #pragma unroll
        for (int w = 0; w < 8; w++)
            #pragma unroll
            for (int i = 0; i < 4; i++)
                s[i] += lds[(w * 32 + rrow) * 66 + rh0 + i];
        #pragma unroll
        for (int i = 0; i < 4; i++)
            ws[(size_t)(m0 + rrow) * 64 + rh0 + i] = f2bf(s[i]);
    }
    __syncthreads();

    // ---- phase K ----
    #pragma unroll
    for (int tf = 0; tf < 2; tf++)
        #pragma unroll
        for (int nt = 0; nt < 4; nt++)
            #pragma unroll
            for (int r = 0; r < 4; r++)
                lds[(wave * 32 + tf * 16 + quad * 4 + r) * 66 + nt * 16 + l16]
                    = ak[tf][nt][r];
    __syncthreads();
    {
        float s[4] = {0.f, 0.f, 0.f, 0.f};
        #pragma unroll
        for (int w = 0; w < 8; w++)
            #pragma unroll
            for (int i = 0; i < 4; i++)
                s[i] += lds[(w * 32 + rrow) * 66 + rh0 + i];
        #pragma unroll
        for (int i = 0; i < 4; i++)
            ws[NTOT + (size_t)(m0 + rrow) * 64 + rh0 + i] = f2bf(s[i]);
    }
    __syncthreads();

    // ---- phase V: av[nt][tf][r] -> h = nt*16+quad*4+r, t = tf*16+l16 ----
    #pragma unroll
    for (int nt = 0; nt < 4; nt++)
        #pragma unroll
        for (int tf = 0; tf < 2; tf++)
            #pragma unroll
            for (int r = 0; r < 4; r++)
                lds[(wave * 64 + nt * 16 + quad * 4 + r) * 33 + tf * 16 + l16]
                    = av[nt][tf][r];
    __syncthreads();
    {
        const int h = tid >> 3, t0 = (tid & 7) * 4;
        unsigned short* vdst = ws + 2 * NTOT + (size_t)b * 131072
                             + (size_t)h * 2048 + tb0;
        float s[4] = {0.f, 0.f, 0.f, 0.f};
        #pragma unroll
        for (int w = 0; w < 8; w++)
            #pragma unroll
            for (int i = 0; i < 4; i++)
                s[i] += lds[(w * 64 + h) * 33 + t0 + i];
        #pragma unroll
        for (int i = 0; i < 4; i++)
            vdst[t0 + i] = f2bf(s[i]);
    }
}

// ---------------------------------------------------------------------------
// Kernel 2: fused flash attention, 8-way in-block K-split + XCD swizzle.
// Exact proven baseline body (setprio removed: measured neutral in round-5).
// ---------------------------------------------------------------------------
__global__ __launch_bounds__(512) void attn_fused_kernel(
    const unsigned short* __restrict__ ws, float* __restrict__ out)
{
    const int B    = blockIdx.x;
    const int xcd  = B & 7;
    const int slot = B >> 3;
    const int b    = xcd & 3;
    const int qt   = (slot << 1) | (xcd >> 2);   // 0..127
    const int q0 = qt * 16;
    const int tid  = threadIdx.x;
    const int wave = tid >> 6, lane = tid & 63;  // wave 0..7
    const int quad = lane >> 4, l16 = lane & 15;

    const unsigned short* Q  = ws + (size_t)b * 131072;
    const unsigned short* K  = ws + NTOT + (size_t)b * 131072;
    const unsigned short* VT = ws + 2 * NTOT + (size_t)b * 131072;

    __shared__ unsigned short p_lds[8][16][72];  // per-wave P scratch
    __shared__ float o_red[8][16][68];           // per-wave partial O
    __shared__ float ml_red[8][2][16];           // per-wave m / l

    const int qrow = q0 + l16;
    short8 qf0 = *(const short8*)(Q + (size_t)qrow * 64 + quad * 8);
    short8 qf1 = *(const short8*)(Q + (size_t)qrow * 64 + 32 + quad * 8);

    f32x4 o[4] = {};
    float m_i[4], l_i[4];
    #pragma unroll
    for (int r = 0; r < 4; r++) { m_i[r] = -1e30f; l_i[r] = 0.f; }

    const int qi = q0 + quad * 4;
    const int nkt = (qt >> 2) + 1;

    for (int t = wave; t < nkt; t += 8) {
        const int j0 = t * 64;
        f32x4 s[4] = {};
        #pragma unroll
        for (int nt = 0; nt < 4; nt++) {
            const unsigned short* kp = K + (size_t)(j0 + nt * 16 + l16) * 64 + quad * 8;
            short8 kf0 = *(const short8*)(kp);
            short8 kf1 = *(const short8*)(kp + 32);
            s[nt] = __builtin_amdgcn_mfma_f32_16x16x32_bf16(qf0, kf0, s[nt], 0, 0, 0);
            s[nt] = __builtin_amdgcn_mfma_f32_16x16x32_bf16(qf1, kf1, s[nt], 0, 0, 0);
        }
        float pm[4] = {-1e30f, -1e30f, -1e30f, -1e30f};
        #pragma unroll
        for (int nt = 0; nt < 4; nt++) {
            const int kj = j0 + nt * 16 + l16;
            #pragma unroll
            for (int r = 0; r < 4; r++) {
                float v = s[nt][r] * 0.125f;
                v = (kj > qi + r || v == 0.0f) ? -1e30f : v;  // causal + ==0 quirk
                s[nt][r] = v;
                pm[r] = fmaxf(pm[r], v);
            }
        }
        #pragma unroll
        for (int off = 1; off < 16; off <<= 1)
            #pragma unroll
            for (int r = 0; r < 4; r++)
                pm[r] = fmaxf(pm[r], __shfl_xor(pm[r], off));
        float alpha[4];
        #pragma unroll
        for (int r = 0; r < 4; r++) {
            float mn = fmaxf(m_i[r], pm[r]);
            alpha[r] = __expf(m_i[r] - mn);
            m_i[r] = mn;
        }
        float ps[4] = {0.f, 0.f, 0.f, 0.f};
        #pragma unroll
        for (int nt = 0; nt < 4; nt++)
            #pragma unroll
            for (int r = 0; r < 4; r++) {
                float p = __expf(s[nt][r] - m_i[r]);
                ps[r] += p;
                p_lds[wave][quad * 4 + r][nt * 16 + l16] = f2bf(p);
            }
        #pragma unroll
        for (int off = 1; off < 16; off <<= 1)
            #pragma unroll
            for (int r = 0; r < 4; r++)
                ps[r] += __shfl_xor(ps[r], off);
        #pragma unroll
        for (int r = 0; r < 4; r++) l_i[r] = l_i[r] * alpha[r] + ps[r];
        #pragma unroll
        for (int ht = 0; ht < 4; ht++)
            #pragma unroll
            for (int r = 0; r < 4; r++)
                o[ht][r] *= alpha[r];
        #pragma unroll
        for (int ks = 0; ks < 2; ks++) {
            short8 pf = *(const short8*)&p_lds[wave][l16][ks * 32 + quad * 8];
            #pragma unroll
            for (int ht = 0; ht < 4; ht++) {
                short8 vf = *(const short8*)(VT + (size_t)(ht * 16 + l16) * 2048 + j0 + ks * 32 + quad * 8);
                o[ht] = __builtin_amdgcn_mfma_f32_16x16x32_bf16(pf, vf, o[ht], 0, 0, 0);
            }
        }
    }

    // ---- stash per-wave partial state ----
    #pragma unroll
    for (int ht = 0; ht < 4; ht++)
        #pragma unroll
        for (int r = 0; r < 4; r++)
            o_red[wave][quad * 4 + r][ht * 16 + l16] = o[ht][r];
    if (l16 == 0) {
        #pragma unroll
        for (int r = 0; r < 4; r++) {
            ml_red[wave][0][quad * 4 + r] = m_i[r];
            ml_red[wave][1][quad * 4 + r] = l_i[r];
        }
    }
    __syncthreads();

    // ---- 8-way combine: thread -> (row = tid>>5, col0 = (tid&31)*2) ----
    const int row = tid >> 5, c0 = (tid & 31) * 2;
    float M = -1e30f;
    #pragma unroll
    for (int w = 0; w < 8; w++) M = fmaxf(M, ml_red[w][0][row]);
    float wgt[8];
    float l = 0.f;
    #pragma unroll
    for (int w = 0; w < 8; w++) {
        wgt[w] = __expf(ml_red[w][0][row] - M);
        l += wgt[w] * ml_red[w][1][row];
    }
    const float inv = 1.0f / l;
    float* op = out + ((size_t)b * 2048 + q0 + row) * 64 + c0;
    #pragma unroll
    for (int i = 0; i < 2; i++) {
        const int col = c0 + i;
        float sv = 0.f;
        #pragma unroll
        for (int w = 0; w < 8; w++) sv += wgt[w] * o_red[w][row][col];
        op[i] = sv * inv;
    }
}

// ---------------------------------------------------------------------------
extern "C" void kernel_launch(void* const* d_in, const int* in_sizes, int n_in,
                              void* d_out, int out_size, void* d_ws, size_t ws_size,
                              hipStream_t stream) {
    const float* x  = (const float*)d_in[0];
    const float* Wq = (const float*)d_in[1];
    const float* Wk = (const float*)d_in[2];
    const float* Wv = (const float*)d_in[3];
    float* out = (float*)d_out;
    unsigned short* ws = (unsigned short*)d_ws;

    projw_kernel<<<dim3(256), 512, 0, stream>>>(x, Wq, Wk, Wv, ws);
    attn_fused_kernel<<<dim3(512), 512, 0, stream>>>(ws, out);
}

// Round 13
// 159.588 us; speedup vs baseline: 1.0037x; 1.0037x over previous
//
#include <hip/hip_runtime.h>

// B=4, T=2048, C=1024, H=64. fp32 in/out, bf16 MFMA internally.
// ws layout (u16 elements):
//   [0,        524288)  q  bf16  [b*2048+t][64]
//   [524288,  1048576)  k  bf16  [b*2048+t][64]
//   [1048576, 1572864)  vT bf16  [b][h][t]   (b*131072 + h*2048 + t)
//   [1572864, 1769472)  wT bf16  [sel][h][c] (sel*65536 + h*1024 + c)
//   byte 4 MB: 48 u32 ready-tokens (poison-safe MAGIC handshake)
//
// Round-13 = round-12 resubmission (12 died on GPU acquisition timeout;
// never ran). Fixes round-9's projw=69us regression. Diagnosis from round-9
// counters: VGPR_Count=80 < 96 VGPRs of live accumulators -> the compiler
// SPILLED acc to scratch (each MFMA C-in gated on a ~200cy scratch load at
// 1 block/CU). Fixes: (1) __launch_bounds__(512,2) -> allocator may use up
// to 256 VGPRs, no spill; (2) poll moved BEFORE any proj state (minimal
// live range across the spin; proj body byte-exact baseline, own prefetch);
// (3) tokens AGENT->SYSTEM scope (belt-and-braces visibility).
// Expected: projw ~18-25us, VGPR >=160, total ~112-117 (baseline 119.2).

typedef __attribute__((ext_vector_type(8))) short short8;
typedef __attribute__((ext_vector_type(4))) float f32x4;

#define NTOT 524288   // 8192*64
#define WT_OFF (3 * NTOT)
#define TOKEN_MAGIC 0x4D5A9E21u     // 4 distinct bytes: no byte/dword poison fill can alias it
#define TOKEN_U16_OFF 2097152       // byte offset 4 MB into ws (past wT end at 1966080)

__device__ __forceinline__ unsigned short f2bf(float f) {
    unsigned int u = __builtin_bit_cast(unsigned int, f);
    return (unsigned short)((u + 0x7fffu + ((u >> 16) & 1u)) >> 16);
}

__device__ __forceinline__ short8 pack8(float4 a, float4 b) {
    short8 r;
    r[0] = (short)f2bf(a.x); r[1] = (short)f2bf(a.y);
    r[2] = (short)f2bf(a.z); r[3] = (short)f2bf(a.w);
    r[4] = (short)f2bf(b.x); r[5] = (short)f2bf(b.y);
    r[6] = (short)f2bf(b.z); r[7] = (short)f2bf(b.w);
    return r;
}

// ---------------------------------------------------------------------------
// Kernel 1: fused W-transpose + projections. 256 blocks x 512 threads.
// Blocks 0..47 transpose one 64-column tile of one W matrix and publish a
// SYSTEM-scope release token. All blocks: poll the 48 tokens, then run the
// byte-exact baseline 32-row proj body. __launch_bounds__(512,2) keeps the
// 96-VGPR accumulator set in registers (round-9's VGPR=80 spill regression).
// Deadlock-safe: 67.6 KB LDS -> 1 block/CU, grid 256 = capacity, all blocks
// co-resident; producers are the first dispatched.
// ---------------------------------------------------------------------------
__global__ __launch_bounds__(512, 2) void projw_kernel(
    const float* __restrict__ x, const float* __restrict__ Wq,
    const float* __restrict__ Wk, const float* __restrict__ Wv,
    unsigned short* __restrict__ ws)
{
    const int blk  = blockIdx.x;
    const int m0   = blk * 32;
    const int tid  = threadIdx.x;
    const int wave = tid >> 6, lane = tid & 63;   // wave 0..7
    const int quad = lane >> 4, l16 = lane & 15;

    unsigned short* wt = ws + WT_OFF;
    unsigned int* tokens = (unsigned int*)(ws + TOKEN_U16_OFF);

    // shared scratch:
    //   wtrans phase (blocks 0..47): u16 tile[64][72] = 9216 B (aliased)
    //   q/k phases: [8][32][66] floats; v phase: [8][64][33] floats
    __shared__ float lds[16896];   // 67.6 KB

    // ---- phase A: W transpose (blocks 0..47 only; block-uniform branch) ----
    if (blk < 48) {
        const int sel = blk >> 4;            // 0..2
        const int c0  = (blk & 15) * 64;     // 0..960
        const float* W = (sel == 0) ? Wq : ((sel == 1) ? Wk : Wv);
        unsigned short (*tile)[72] = (unsigned short (*)[72])lds;
        if (tid < 256) {
            const int c  = tid >> 2;
            const int hg = (tid & 3) * 16;
            const float* src = W + (size_t)(c0 + c) * 64 + hg;
            #pragma unroll
            for (int i = 0; i < 16; i++) tile[c][hg + i] = f2bf(src[i]);
        }
        __syncthreads();
        if (tid < 256) {
            const int h   = tid >> 2;
            const int cg0 = (tid & 3) * 16;
            unsigned short* dst = wt + ((size_t)sel * 64 + h) * 1024 + c0 + cg0;
            #pragma unroll
            for (int i = 0; i < 16; i++) dst[i] = tile[cg0 + i][h];
        }
        __syncthreads();   // drains vmcnt: all wT stores of this block issued
        if (tid == 0) {
            __threadfence();   // release: write back producer L2 (wT data)
            __hip_atomic_store(&tokens[blk], TOKEN_MAGIC,
                               __ATOMIC_RELEASE, __HIP_MEMORY_SCOPE_SYSTEM);
        }
    }

    // ---- wait for all 48 wT tiles (SYSTEM acquire), minimal live state ----
    if (tid < 48) {
        while (__hip_atomic_load(&tokens[tid], __ATOMIC_ACQUIRE,
                                 __HIP_MEMORY_SCOPE_SYSTEM) != TOKEN_MAGIC)
            __builtin_amdgcn_s_sleep(1);
    }
    __syncthreads();
    __threadfence();   // acquire side for all threads: invalidate stale lines

    const unsigned short* wq = wt;
    const unsigned short* wk = wt + 65536;
    const unsigned short* wv = wt + 131072;

    // ---- byte-exact baseline 32-row proj body (own prefetch) ----
    f32x4 aq[2][4] = {}, ak[2][4] = {}, av[4][2] = {};

    const int kbase = wave * 128;
    const float* xrow0 = x + (size_t)(m0 + l16) * 1024 + kbase + quad * 8;
    const float* xrow1 = xrow0 + (size_t)16 * 1024;
    float4 xa0 = *(const float4*)(xrow0);
    float4 xb0 = *(const float4*)(xrow0 + 4);
    float4 xa1 = *(const float4*)(xrow1);
    float4 xb1 = *(const float4*)(xrow1 + 4);
    for (int kk = 0; kk < 128; kk += 32) {
        const int nk = (kk + 32) & 127;     // wraps on last iter (unused)
        float4 na0 = *(const float4*)(xrow0 + nk);
        float4 nb0 = *(const float4*)(xrow0 + nk + 4);
        float4 na1 = *(const float4*)(xrow1 + nk);
        float4 nb1 = *(const float4*)(xrow1 + nk + 4);
        short8 af0 = pack8(xa0, xb0);
        short8 af1 = pack8(xa1, xb1);
        const int wo = kbase + kk + quad * 8;
        #pragma unroll
        for (int nt = 0; nt < 4; nt++) {
            const size_t ro = (size_t)(nt * 16 + l16) * 1024 + wo;
            short8 bq = *(const short8*)(wq + ro);
            short8 bk = *(const short8*)(wk + ro);
            short8 bv = *(const short8*)(wv + ro);
            aq[0][nt] = __builtin_amdgcn_mfma_f32_16x16x32_bf16(af0, bq, aq[0][nt], 0, 0, 0);
            aq[1][nt] = __builtin_amdgcn_mfma_f32_16x16x32_bf16(af1, bq, aq[1][nt], 0, 0, 0);
            ak[0][nt] = __builtin_amdgcn_mfma_f32_16x16x32_bf16(af0, bk, ak[0][nt], 0, 0, 0);
            ak[1][nt] = __builtin_amdgcn_mfma_f32_16x16x32_bf16(af1, bk, ak[1][nt], 0, 0, 0);
            av[nt][0] = __builtin_amdgcn_mfma_f32_16x16x32_bf16(bv, af0, av[nt][0], 0, 0, 0);
            av[nt][1] = __builtin_amdgcn_mfma_f32_16x16x32_bf16(bv, af1, av[nt][1], 0, 0, 0);
        }
        xa0 = na0; xb0 = nb0; xa1 = na1; xb1 = nb1;
    }

    const int b   = m0 >> 11;
    const int tb0 = m0 & 2047;
    const int rrow = tid >> 4, rh0 = (tid & 15) * 4;   // q/k reduce mapping

    __syncthreads();   // re-convergence before LDS reuse (tile alias done)

    // ---- phase Q: stash, reduce 8-way, store ----
    #pragma unroll
    for (int tf = 0; tf < 2; tf++)
        #pragma unroll
        for (int nt = 0; nt < 4; nt++)
            #pragma unroll
            for (int r = 0; r < 4; r++)
                lds[(wave * 32 + tf * 16 + quad * 4 + r) * 66 + nt * 16 + l16]
                    = aq[tf][nt][r];
    __syncthreads();
    {
        float s[4] = {0.f, 0.f, 0.f, 0.f};
        #pragma unroll
        for (int w = 0; w < 8; w++)
            #pragma unroll
            for (int i = 0; i < 4; i++)
                s[i] += lds[(w * 32 + rrow) * 66 + rh0 + i];
        #pragma unroll
        for (int i = 0; i < 4; i++)
            ws[(size_t)(m0 + rrow) * 64 + rh0 + i] = f2bf(s[i]);
    }
    __syncthreads();

    // ---- phase K ----
    #pragma unroll
    for (int tf = 0; tf < 2; tf++)
        #pragma unroll
        for (int nt = 0; nt < 4; nt++)
            #pragma unroll
            for (int r = 0; r < 4; r++)
                lds[(wave * 32 + tf * 16 + quad * 4 + r) * 66 + nt * 16 + l16]
                    = ak[tf][nt][r];
    __syncthreads();
    {
        float s[4] = {0.f, 0.f, 0.f, 0.f};
        #pragma unroll
        for (int w = 0; w < 8; w++)
            #pragma unroll
            for (int i = 0; i < 4; i++)
                s[i] += lds[(w * 32 + rrow) * 66 + rh0 + i];
        #pragma unroll
        for (int i = 0; i < 4; i++)
            ws[NTOT + (size_t)(m0 + rrow) * 64 + rh0 + i] = f2bf(s[i]);
    }
    __syncthreads();

    // ---- phase V: av[nt][tf][r] -> h = nt*16+quad*4+r, t = tf*16+l16 ----
    #pragma unroll
    for (int nt = 0; nt < 4; nt++)
        #pragma unroll
        for (int tf = 0; tf < 2; tf++)
            #pragma unroll
            for (int r = 0; r < 4; r++)
                lds[(wave * 64 + nt * 16 + quad * 4 + r) * 33 + tf * 16 + l16]
                    = av[nt][tf][r];
    __syncthreads();
    {
        const int h = tid >> 3, t0 = (tid & 7) * 4;
        unsigned short* vdst = ws + 2 * NTOT + (size_t)b * 131072
                             + (size_t)h * 2048 + tb0;
        float s[4] = {0.f, 0.f, 0.f, 0.f};
        #pragma unroll
        for (int w = 0; w < 8; w++)
            #pragma unroll
            for (int i = 0; i < 4; i++)
                s[i] += lds[(w * 64 + h) * 33 + t0 + i];
        #pragma unroll
        for (int i = 0; i < 4; i++)
            vdst[t0 + i] = f2bf(s[i]);
    }
}

// ---------------------------------------------------------------------------
// Kernel 2: fused flash attention, 8-way in-block K-split + XCD swizzle.
// Exact proven baseline body (setprio removed: measured neutral in round-5).
// ---------------------------------------------------------------------------
__global__ __launch_bounds__(512) void attn_fused_kernel(
    const unsigned short* __restrict__ ws, float* __restrict__ out)
{
    const int B    = blockIdx.x;
    const int xcd  = B & 7;
    const int slot = B >> 3;
    const int b    = xcd & 3;
    const int qt   = (slot << 1) | (xcd >> 2);   // 0..127
    const int q0 = qt * 16;
    const int tid  = threadIdx.x;
    const int wave = tid >> 6, lane = tid & 63;  // wave 0..7
    const int quad = lane >> 4, l16 = lane & 15;

    const unsigned short* Q  = ws + (size_t)b * 131072;
    const unsigned short* K  = ws + NTOT + (size_t)b * 131072;
    const unsigned short* VT = ws + 2 * NTOT + (size_t)b * 131072;

    __shared__ unsigned short p_lds[8][16][72];  // per-wave P scratch
    __shared__ float o_red[8][16][68];           // per-wave partial O
    __shared__ float ml_red[8][2][16];           // per-wave m / l

    const int qrow = q0 + l16;
    short8 qf0 = *(const short8*)(Q + (size_t)qrow * 64 + quad * 8);
    short8 qf1 = *(const short8*)(Q + (size_t)qrow * 64 + 32 + quad * 8);

    f32x4 o[4] = {};
    float m_i[4], l_i[4];
    #pragma unroll
    for (int r = 0; r < 4; r++) { m_i[r] = -1e30f; l_i[r] = 0.f; }

    const int qi = q0 + quad * 4;
    const int nkt = (qt >> 2) + 1;

    for (int t = wave; t < nkt; t += 8) {
        const int j0 = t * 64;
        f32x4 s[4] = {};
        #pragma unroll
        for (int nt = 0; nt < 4; nt++) {
            const unsigned short* kp = K + (size_t)(j0 + nt * 16 + l16) * 64 + quad * 8;
            short8 kf0 = *(const short8*)(kp);
            short8 kf1 = *(const short8*)(kp + 32);
            s[nt] = __builtin_amdgcn_mfma_f32_16x16x32_bf16(qf0, kf0, s[nt], 0, 0, 0);
            s[nt] = __builtin_amdgcn_mfma_f32_16x16x32_bf16(qf1, kf1, s[nt], 0, 0, 0);
        }
        float pm[4] = {-1e30f, -1e30f, -1e30f, -1e30f};
        #pragma unroll
        for (int nt = 0; nt < 4; nt++) {
            const int kj = j0 + nt * 16 + l16;
            #pragma unroll
            for (int r = 0; r < 4; r++) {
                float v = s[nt][r] * 0.125f;
                v = (kj > qi + r || v == 0.0f) ? -1e30f : v;  // causal + ==0 quirk
                s[nt][r] = v;
                pm[r] = fmaxf(pm[r], v);
            }
        }
        #pragma unroll
        for (int off = 1; off < 16; off <<= 1)
            #pragma unroll
            for (int r = 0; r < 4; r++)
                pm[r] = fmaxf(pm[r], __shfl_xor(pm[r], off));
        float alpha[4];
        #pragma unroll
        for (int r = 0; r < 4; r++) {
            float mn = fmaxf(m_i[r], pm[r]);
            alpha[r] = __expf(m_i[r] - mn);
            m_i[r] = mn;
        }
        float ps[4] = {0.f, 0.f, 0.f, 0.f};
        #pragma unroll
        for (int nt = 0; nt < 4; nt++)
            #pragma unroll
            for (int r = 0; r < 4; r++) {
                float p = __expf(s[nt][r] - m_i[r]);
                ps[r] += p;
                p_lds[wave][quad * 4 + r][nt * 16 + l16] = f2bf(p);
            }
        #pragma unroll
        for (int off = 1; off < 16; off <<= 1)
            #pragma unroll
            for (int r = 0; r < 4; r++)
                ps[r] += __shfl_xor(ps[r], off);
        #pragma unroll
        for (int r = 0; r < 4; r++) l_i[r] = l_i[r] * alpha[r] + ps[r];
        #pragma unroll
        for (int ht = 0; ht < 4; ht++)
            #pragma unroll
            for (int r = 0; r < 4; r++)
                o[ht][r] *= alpha[r];
        #pragma unroll
        for (int ks = 0; ks < 2; ks++) {
            short8 pf = *(const short8*)&p_lds[wave][l16][ks * 32 + quad * 8];
            #pragma unroll
            for (int ht = 0; ht < 4; ht++) {
                short8 vf = *(const short8*)(VT + (size_t)(ht * 16 + l16) * 2048 + j0 + ks * 32 + quad * 8);
                o[ht] = __builtin_amdgcn_mfma_f32_16x16x32_bf16(pf, vf, o[ht], 0, 0, 0);
            }
        }
    }

    // ---- stash per-wave partial state ----
    #pragma unroll
    for (int ht = 0; ht < 4; ht++)
        #pragma unroll
        for (int r = 0; r < 4; r++)
            o_red[wave][quad * 4 + r][ht * 16 + l16] = o[ht][r];
    if (l16 == 0) {
        #pragma unroll
        for (int r = 0; r < 4; r++) {
            ml_red[wave][0][quad * 4 + r] = m_i[r];
            ml_red[wave][1][quad * 4 + r] = l_i[r];
        }
    }
    __syncthreads();

    // ---- 8-way combine: thread -> (row = tid>>5, col0 = (tid&31)*2) ----
    const int row = tid >> 5, c0 = (tid & 31) * 2;
    float M = -1e30f;
    #pragma unroll
    for (int w = 0; w < 8; w++) M = fmaxf(M, ml_red[w][0][row]);
    float wgt[8];
    float l = 0.f;
    #pragma unroll
    for (int w = 0; w < 8; w++) {
        wgt[w] = __expf(ml_red[w][0][row] - M);
        l += wgt[w] * ml_red[w][1][row];
    }
    const float inv = 1.0f / l;
    float* op = out + ((size_t)b * 2048 + q0 + row) * 64 + c0;
    #pragma unroll
    for (int i = 0; i < 2; i++) {
        const int col = c0 + i;
        float sv = 0.f;
        #pragma unroll
        for (int w = 0; w < 8; w++) sv += wgt[w] * o_red[w][row][col];
        op[i] = sv * inv;
    }
}

// ---------------------------------------------------------------------------
extern "C" void kernel_launch(void* const* d_in, const int* in_sizes, int n_in,
                              void* d_out, int out_size, void* d_ws, size_t ws_size,
                              hipStream_t stream) {
    const float* x  = (const float*)d_in[0];
    const float* Wq = (const float*)d_in[1];
    const float* Wk = (const float*)d_in[2];
    const float* Wv = (const float*)d_in[3];
    float* out = (float*)d_out;
    unsigned short* ws = (unsigned short*)d_ws;

    projw_kernel<<<dim3(256), 512, 0, stream>>>(x, Wq, Wk, Wv, ws);
    attn_fused_kernel<<<dim3(512), 512, 0, stream>>>(ws, out);
}

// Round 14
// 127.926 us; speedup vs baseline: 1.2521x; 1.2475x over previous
//
#include <hip/hip_runtime.h>

// B=4, T=2048, C=1024, H=64. fp32 in/out, bf16 MFMA internally.
// ws layout (u16 elements):
//   [0,        524288)  q  bf16  [b*2048+t][64]
//   [524288,  1048576)  k  bf16  [b*2048+t][64]
//   [1048576, 1572864)  vT bf16  [b][h][t]   (b*131072 + h*2048 + t)
//   [1572864, 1769472)  wT bf16  [sel][h][c] (sel*65536 + h*1024 + c)
//   byte 4 MB: 48 u32 ready-tokens (poison-safe MAGIC handshake)
//
// Round-14: round-13 showed launch_bounds(512,2) changed NOTHING (VGPR=80
// both ways -> accumulators live in AGPRs, spill theory dead) and SYSTEM
// scope changed nothing (67us = round-9's 69us). Remaining ~52us idle is the
// handshake machinery. New diagnosis, quantitatively consistent across
// rounds 2/9/13: the ALL-THREADS acquire __threadfence() (131k threads each
// issuing buffer_inv/wbl2, serializing at L2) costs ~50-65us per fence
// point (round-2: 4 such points ~= 260us; round-9/13: 1 point ~= 52us).
// Fixes: (1) acquire fence executed by ONE thread between two barriers
// (cache maintenance is CU/XCD-global, one inv covers the block);
// (2) token handshake via RMW atomics (atomicExch store / atomicOr read)
// which execute at the coherence point and cannot read stale L2 lines.
// Expected: projw ~15-22us, total ~105-114us (baseline 119.2).

typedef __attribute__((ext_vector_type(8))) short short8;
typedef __attribute__((ext_vector_type(4))) float f32x4;

#define NTOT 524288   // 8192*64
#define WT_OFF (3 * NTOT)
#define TOKEN_MAGIC 0x4D5A9E21u     // 4 distinct bytes: no byte/dword poison fill can alias it
#define TOKEN_U16_OFF 2097152       // byte offset 4 MB into ws (past wT end at 1966080)

__device__ __forceinline__ unsigned short f2bf(float f) {
    unsigned int u = __builtin_bit_cast(unsigned int, f);
    return (unsigned short)((u + 0x7fffu + ((u >> 16) & 1u)) >> 16);
}

__device__ __forceinline__ short8 pack8(float4 a, float4 b) {
    short8 r;
    r[0] = (short)f2bf(a.x); r[1] = (short)f2bf(a.y);
    r[2] = (short)f2bf(a.z); r[3] = (short)f2bf(a.w);
    r[4] = (short)f2bf(b.x); r[5] = (short)f2bf(b.y);
    r[6] = (short)f2bf(b.z); r[7] = (short)f2bf(b.w);
    return r;
}

// ---------------------------------------------------------------------------
// Kernel 1: fused W-transpose + projections. 256 blocks x 512 threads.
// Blocks 0..47 transpose one 64-column tile of one W matrix, release-fence
// (tid==0 only), and publish via atomicExch (RMW -> coherence point).
// All blocks: tid<48 poll their slot via atomicOr(p,0) RMW reads (never
// stale), then ONE thread runs the acquire __threadfence between two
// barriers, then the byte-exact baseline 32-row proj body runs.
// Deadlock-safe: 67.6 KB LDS -> 1 block/CU, grid 256 = capacity, all blocks
// co-resident; producers are the first dispatched.
// ---------------------------------------------------------------------------
__global__ __launch_bounds__(512, 2) void projw_kernel(
    const float* __restrict__ x, const float* __restrict__ Wq,
    const float* __restrict__ Wk, const float* __restrict__ Wv,
    unsigned short* __restrict__ ws)
{
    const int blk  = blockIdx.x;
    const int m0   = blk * 32;
    const int tid  = threadIdx.x;
    const int wave = tid >> 6, lane = tid & 63;   // wave 0..7
    const int quad = lane >> 4, l16 = lane & 15;

    unsigned short* wt = ws + WT_OFF;
    unsigned int* tokens = (unsigned int*)(ws + TOKEN_U16_OFF);

    // shared scratch:
    //   wtrans phase (blocks 0..47): u16 tile[64][72] = 9216 B (aliased)
    //   q/k phases: [8][32][66] floats; v phase: [8][64][33] floats
    __shared__ float lds[16896];   // 67.6 KB

    // ---- phase A: W transpose (blocks 0..47 only; block-uniform branch) ----
    if (blk < 48) {
        const int sel = blk >> 4;            // 0..2
        const int c0  = (blk & 15) * 64;     // 0..960
        const float* W = (sel == 0) ? Wq : ((sel == 1) ? Wk : Wv);
        unsigned short (*tile)[72] = (unsigned short (*)[72])lds;
        if (tid < 256) {
            const int c  = tid >> 2;
            const int hg = (tid & 3) * 16;
            const float* src = W + (size_t)(c0 + c) * 64 + hg;
            #pragma unroll
            for (int i = 0; i < 16; i++) tile[c][hg + i] = f2bf(src[i]);
        }
        __syncthreads();
        if (tid < 256) {
            const int h   = tid >> 2;
            const int cg0 = (tid & 3) * 16;
            unsigned short* dst = wt + ((size_t)sel * 64 + h) * 1024 + c0 + cg0;
            #pragma unroll
            for (int i = 0; i < 16; i++) dst[i] = tile[cg0 + i][h];
        }
        __syncthreads();   // drains vmcnt: all wT stores of this block in L2
        if (tid == 0) {
            __threadfence();   // single-thread release: write back dirty L2 (wT)
            atomicExch(&tokens[blk], TOKEN_MAGIC);   // RMW: lands at coherence point
        }
    }

    // ---- wait for all 48 wT tiles: RMW reads, never stale ----
    if (tid < 48) {
        while (atomicOr(&tokens[tid], 0u) != TOKEN_MAGIC)
            __builtin_amdgcn_s_sleep(8);
    }
    __syncthreads();
    if (tid == 0) __threadfence();   // single-thread acquire: invalidate stale
    __syncthreads();                 // lines for the whole CU (L1/XCD L2)

    const unsigned short* wq = wt;
    const unsigned short* wk = wt + 65536;
    const unsigned short* wv = wt + 131072;

    // ---- byte-exact baseline 32-row proj body (own prefetch) ----
    f32x4 aq[2][4] = {}, ak[2][4] = {}, av[4][2] = {};

    const int kbase = wave * 128;
    const float* xrow0 = x + (size_t)(m0 + l16) * 1024 + kbase + quad * 8;
    const float* xrow1 = xrow0 + (size_t)16 * 1024;
    float4 xa0 = *(const float4*)(xrow0);
    float4 xb0 = *(const float4*)(xrow0 + 4);
    float4 xa1 = *(const float4*)(xrow1);
    float4 xb1 = *(const float4*)(xrow1 + 4);
    for (int kk = 0; kk < 128; kk += 32) {
        const int nk = (kk + 32) & 127;     // wraps on last iter (unused)
        float4 na0 = *(const float4*)(xrow0 + nk);
        float4 nb0 = *(const float4*)(xrow0 + nk + 4);
        float4 na1 = *(const float4*)(xrow1 + nk);
        float4 nb1 = *(const float4*)(xrow1 + nk + 4);
        short8 af0 = pack8(xa0, xb0);
        short8 af1 = pack8(xa1, xb1);
        const int wo = kbase + kk + quad * 8;
        #pragma unroll
        for (int nt = 0; nt < 4; nt++) {
            const size_t ro = (size_t)(nt * 16 + l16) * 1024 + wo;
            short8 bq = *(const short8*)(wq + ro);
            short8 bk = *(const short8*)(wk + ro);
            short8 bv = *(const short8*)(wv + ro);
            aq[0][nt] = __builtin_amdgcn_mfma_f32_16x16x32_bf16(af0, bq, aq[0][nt], 0, 0, 0);
            aq[1][nt] = __builtin_amdgcn_mfma_f32_16x16x32_bf16(af1, bq, aq[1][nt], 0, 0, 0);
            ak[0][nt] = __builtin_amdgcn_mfma_f32_16x16x32_bf16(af0, bk, ak[0][nt], 0, 0, 0);
            ak[1][nt] = __builtin_amdgcn_mfma_f32_16x16x32_bf16(af1, bk, ak[1][nt], 0, 0, 0);
            av[nt][0] = __builtin_amdgcn_mfma_f32_16x16x32_bf16(bv, af0, av[nt][0], 0, 0, 0);
            av[nt][1] = __builtin_amdgcn_mfma_f32_16x16x32_bf16(bv, af1, av[nt][1], 0, 0, 0);
        }
        xa0 = na0; xb0 = nb0; xa1 = na1; xb1 = nb1;
    }

    const int b   = m0 >> 11;
    const int tb0 = m0 & 2047;
    const int rrow = tid >> 4, rh0 = (tid & 15) * 4;   // q/k reduce mapping

    __syncthreads();   // re-convergence before LDS reuse (tile alias done)

    // ---- phase Q: stash, reduce 8-way, store ----
    #pragma unroll
    for (int tf = 0; tf < 2; tf++)
        #pragma unroll
        for (int nt = 0; nt < 4; nt++)
            #pragma unroll
            for (int r = 0; r < 4; r++)
                lds[(wave * 32 + tf * 16 + quad * 4 + r) * 66 + nt * 16 + l16]
                    = aq[tf][nt][r];
    __syncthreads();
    {
        float s[4] = {0.f, 0.f, 0.f, 0.f};
        #pragma unroll
        for (int w = 0; w < 8; w++)
            #pragma unroll
            for (int i = 0; i < 4; i++)
                s[i] += lds[(w * 32 + rrow) * 66 + rh0 + i];
        #pragma unroll
        for (int i = 0; i < 4; i++)
            ws[(size_t)(m0 + rrow) * 64 + rh0 + i] = f2bf(s[i]);
    }
    __syncthreads();

    // ---- phase K ----
    #pragma unroll
    for (int tf = 0; tf < 2; tf++)
        #pragma unroll
        for (int nt = 0; nt < 4; nt++)
            #pragma unroll
            for (int r = 0; r < 4; r++)
                lds[(wave * 32 + tf * 16 + quad * 4 + r) * 66 + nt * 16 + l16]
                    = ak[tf][nt][r];
    __syncthreads();
    {
        float s[4] = {0.f, 0.f, 0.f, 0.f};
        #pragma unroll
        for (int w = 0; w < 8; w++)
            #pragma unroll
            for (int i = 0; i < 4; i++)
                s[i] += lds[(w * 32 + rrow) * 66 + rh0 + i];
        #pragma unroll
        for (int i = 0; i < 4; i++)
            ws[NTOT + (size_t)(m0 + rrow) * 64 + rh0 + i] = f2bf(s[i]);
    }
    __syncthreads();

    // ---- phase V: av[nt][tf][r] -> h = nt*16+quad*4+r, t = tf*16+l16 ----
    #pragma unroll
    for (int nt = 0; nt < 4; nt++)
        #pragma unroll
        for (int tf = 0; tf < 2; tf++)
            #pragma unroll
            for (int r = 0; r < 4; r++)
                lds[(wave * 64 + nt * 16 + quad * 4 + r) * 33 + tf * 16 + l16]
                    = av[nt][tf][r];
    __syncthreads();
    {
        const int h = tid >> 3, t0 = (tid & 7) * 4;
        unsigned short* vdst = ws + 2 * NTOT + (size_t)b * 131072
                             + (size_t)h * 2048 + tb0;
        float s[4] = {0.f, 0.f, 0.f, 0.f};
        #pragma unroll
        for (int w = 0; w < 8; w++)
            #pragma unroll
            for (int i = 0; i < 4; i++)
                s[i] += lds[(w * 64 + h) * 33 + t0 + i];
        #pragma unroll
        for (int i = 0; i < 4; i++)
            vdst[t0 + i] = f2bf(s[i]);
    }
}

// ---------------------------------------------------------------------------
// Kernel 2: fused flash attention, 8-way in-block K-split + XCD swizzle.
// Exact proven baseline body (setprio removed: measured neutral in round-5).
// ---------------------------------------------------------------------------
__global__ __launch_bounds__(512) void attn_fused_kernel(
    const unsigned short* __restrict__ ws, float* __restrict__ out)
{
    const int B    = blockIdx.x;
    const int xcd  = B & 7;
    const int slot = B >> 3;
    const int b    = xcd & 3;
    const int qt   = (slot << 1) | (xcd >> 2);   // 0..127
    const int q0 = qt * 16;
    const int tid  = threadIdx.x;
    const int wave = tid >> 6, lane = tid & 63;  // wave 0..7
    const int quad = lane >> 4, l16 = lane & 15;

    const unsigned short* Q  = ws + (size_t)b * 131072;
    const unsigned short* K  = ws + NTOT + (size_t)b * 131072;
    const unsigned short* VT = ws + 2 * NTOT + (size_t)b * 131072;

    __shared__ unsigned short p_lds[8][16][72];  // per-wave P scratch
    __shared__ float o_red[8][16][68];           // per-wave partial O
    __shared__ float ml_red[8][2][16];           // per-wave m / l

    const int qrow = q0 + l16;
    short8 qf0 = *(const short8*)(Q + (size_t)qrow * 64 + quad * 8);
    short8 qf1 = *(const short8*)(Q + (size_t)qrow * 64 + 32 + quad * 8);

    f32x4 o[4] = {};
    float m_i[4], l_i[4];
    #pragma unroll
    for (int r = 0; r < 4; r++) { m_i[r] = -1e30f; l_i[r] = 0.f; }

    const int qi = q0 + quad * 4;
    const int nkt = (qt >> 2) + 1;

    for (int t = wave; t < nkt; t += 8) {
        const int j0 = t * 64;
        f32x4 s[4] = {};
        #pragma unroll
        for (int nt = 0; nt < 4; nt++) {
            const unsigned short* kp = K + (size_t)(j0 + nt * 16 + l16) * 64 + quad * 8;
            short8 kf0 = *(const short8*)(kp);
            short8 kf1 = *(const short8*)(kp + 32);
            s[nt] = __builtin_amdgcn_mfma_f32_16x16x32_bf16(qf0, kf0, s[nt], 0, 0, 0);
            s[nt] = __builtin_amdgcn_mfma_f32_16x16x32_bf16(qf1, kf1, s[nt], 0, 0, 0);
        }
        float pm[4] = {-1e30f, -1e30f, -1e30f, -1e30f};
        #pragma unroll
        for (int nt = 0; nt < 4; nt++) {
            const int kj = j0 + nt * 16 + l16;
            #pragma unroll
            for (int r = 0; r < 4; r++) {
                float v = s[nt][r] * 0.125f;
                v = (kj > qi + r || v == 0.0f) ? -1e30f : v;  // causal + ==0 quirk
                s[nt][r] = v;
                pm[r] = fmaxf(pm[r], v);
            }
        }
        #pragma unroll
        for (int off = 1; off < 16; off <<= 1)
            #pragma unroll
            for (int r = 0; r < 4; r++)
                pm[r] = fmaxf(pm[r], __shfl_xor(pm[r], off));
        float alpha[4];
        #pragma unroll
        for (int r = 0; r < 4; r++) {
            float mn = fmaxf(m_i[r], pm[r]);
            alpha[r] = __expf(m_i[r] - mn);
            m_i[r] = mn;
        }
        float ps[4] = {0.f, 0.f, 0.f, 0.f};
        #pragma unroll
        for (int nt = 0; nt < 4; nt++)
            #pragma unroll
            for (int r = 0; r < 4; r++) {
                float p = __expf(s[nt][r] - m_i[r]);
                ps[r] += p;
                p_lds[wave][quad * 4 + r][nt * 16 + l16] = f2bf(p);
            }
        #pragma unroll
        for (int off = 1; off < 16; off <<= 1)
            #pragma unroll
            for (int r = 0; r < 4; r++)
                ps[r] += __shfl_xor(ps[r], off);
        #pragma unroll
        for (int r = 0; r < 4; r++) l_i[r] = l_i[r] * alpha[r] + ps[r];
        #pragma unroll
        for (int ht = 0; ht < 4; ht++)
            #pragma unroll
            for (int r = 0; r < 4; r++)
                o[ht][r] *= alpha[r];
        #pragma unroll
        for (int ks = 0; ks < 2; ks++) {
            short8 pf = *(const short8*)&p_lds[wave][l16][ks * 32 + quad * 8];
            #pragma unroll
            for (int ht = 0; ht < 4; ht++) {
                short8 vf = *(const short8*)(VT + (size_t)(ht * 16 + l16) * 2048 + j0 + ks * 32 + quad * 8);
                o[ht] = __builtin_amdgcn_mfma_f32_16x16x32_bf16(pf, vf, o[ht], 0, 0, 0);
            }
        }
    }

    // ---- stash per-wave partial state ----
    #pragma unroll
    for (int ht = 0; ht < 4; ht++)
        #pragma unroll
        for (int r = 0; r < 4; r++)
            o_red[wave][quad * 4 + r][ht * 16 + l16] = o[ht][r];
    if (l16 == 0) {
        #pragma unroll
        for (int r = 0; r < 4; r++) {
            ml_red[wave][0][quad * 4 + r] = m_i[r];
            ml_red[wave][1][quad * 4 + r] = l_i[r];
        }
    }
    __syncthreads();

    // ---- 8-way combine: thread -> (row = tid>>5, col0 = (tid&31)*2) ----
    const int row = tid >> 5, c0 = (tid & 31) * 2;
    float M = -1e30f;
    #pragma unroll
    for (int w = 0; w < 8; w++) M = fmaxf(M, ml_red[w][0][row]);
    float wgt[8];
    float l = 0.f;
    #pragma unroll
    for (int w = 0; w < 8; w++) {
        wgt[w] = __expf(ml_red[w][0][row] - M);
        l += wgt[w] * ml_red[w][1][row];
    }
    const float inv = 1.0f / l;
    float* op = out + ((size_t)b * 2048 + q0 + row) * 64 + c0;
    #pragma unroll
    for (int i = 0; i < 2; i++) {
        const int col = c0 + i;
        float sv = 0.f;
        #pragma unroll
        for (int w = 0; w < 8; w++) sv += wgt[w] * o_red[w][row][col];
        op[i] = sv * inv;
    }
}

// ---------------------------------------------------------------------------
extern "C" void kernel_launch(void* const* d_in, const int* in_sizes, int n_in,
                              void* d_out, int out_size, void* d_ws, size_t ws_size,
                              hipStream_t stream) {
    const float* x  = (const float*)d_in[0];
    const float* Wq = (const float*)d_in[1];
    const float* Wk = (const float*)d_in[2];
    const float* Wv = (const float*)d_in[3];
    float* out = (float*)d_out;
    unsigned short* ws = (unsigned short*)d_ws;

    projw_kernel<<<dim3(256), 512, 0, stream>>>(x, Wq, Wk, Wv, ws);
    attn_fused_kernel<<<dim3(512), 512, 0, stream>>>(ws, out);
}